// Round 13
// baseline (261.914 us; speedup 1.0000x reference)
//
#include <hip/hip_runtime.h>

#define B_ 2
#define S_ 2048
#define H_ 2048
#define NH_ 32
#define NKV_ 8
#define HD_ 64

typedef short short8 __attribute__((ext_vector_type(8)));
typedef float f32x4 __attribute__((ext_vector_type(4)));
typedef float f32x16 __attribute__((ext_vector_type(16)));
typedef unsigned int uint4v __attribute__((ext_vector_type(4)));

__device__ __forceinline__ float bf2f(unsigned short u) {
  union { unsigned int i; float f; } v; v.i = ((unsigned int)u) << 16; return v.f;
}
__device__ __forceinline__ unsigned short f2bf(float f) {
  union { float f; unsigned int i; } v; v.f = f;
  unsigned int u = v.i;
  u += 0x7fffu + ((u >> 16) & 1u);
  return (unsigned short)(u >> 16);
}
__device__ __forceinline__ unsigned int cvtpk(float lo, float hi) {
  unsigned int r;
  asm("v_cvt_pk_bf16_f32 %0, %1, %2" : "=v"(r) : "v"(lo), "v"(hi));
  return r;
}
__device__ __forceinline__ void pl32swap(unsigned int& a, unsigned int& b) {
  asm("v_permlane32_swap_b32 %0, %1" : "+v"(a), "+v"(b));
}
__device__ __forceinline__ short8 mkfrag(unsigned a, unsigned b, unsigned c, unsigned d) {
  union { uint4v u; short8 s; } x;
  x.u = (uint4v){a, b, c, d};
  return x.s;
}
__device__ __forceinline__ void gload_lds16(const unsigned short* g, unsigned short* l) {
  __builtin_amdgcn_global_load_lds((const __attribute__((address_space(1))) void*)g,
                                   (__attribute__((address_space(3))) void*)l,
                                   16, 0, 0);
}
#define MFMA32(A, B, C) __builtin_amdgcn_mfma_f32_32x32x16_bf16(A, B, C, 0, 0, 0)
#define BARF() asm volatile("s_barrier" ::: "memory")

// ---------------- A producer: f32 row-major -> bf16 fragment-tile order (BM=256) ----------------
__global__ __launch_bounds__(256) void castA_frag(const float* __restrict__ in,
                                                  unsigned short* __restrict__ out) {
  int c = blockIdx.x * 4 + (threadIdx.x >> 6);   // chunk id [0, 16384)
  int l = threadIdx.x & 63;
  int D = c & 31, KT = (c >> 5) & 31, bm = c >> 10;
  int row = bm * 256 + ((D >> 4) & 1) * 128 + ((D >> 3) & 1) * 64 + ((D >> 1) & 3) * 16 + (l & 15);
  int k = KT * 64 + (D & 1) * 32 + (l >> 4) * 8;
  const float* src = in + (size_t)row * 2048 + k;
  float4 v0 = *(const float4*)src;
  float4 v1 = *(const float4*)(src + 4);
  ushort4 o0, o1;
  o0.x = f2bf(v0.x); o0.y = f2bf(v0.y); o0.z = f2bf(v0.z); o0.w = f2bf(v0.w);
  o1.x = f2bf(v1.x); o1.y = f2bf(v1.y); o1.z = f2bf(v1.z); o1.w = f2bf(v1.w);
  unsigned short* dst = out + (size_t)c * 512 + l * 8;
  *(ushort4*)dst = o0;
  *(ushort4*)(dst + 4) = o1;
}

// ---------------- W producer: f32 W[K][N] (concat cols) -> bf16 fragment-tile (BN=256) ----------------
__global__ __launch_bounds__(256) void castW_frag(const float* __restrict__ W0,
                                                  const float* __restrict__ W1,
                                                  const float* __restrict__ W2,
                                                  unsigned short* __restrict__ out) {
  __shared__ float tile[64][33];
  int c = blockIdx.x;
  int ngroup = c & 7, KT = (c >> 3) & 31, bn = c >> 8;
  int n0 = bn * 256 + ngroup * 32;
  const float* W; int Nw, nb;
  if (n0 < 2048)      { W = W0; Nw = 2048; nb = n0; }
  else if (n0 < 2560) { W = W1; Nw = 512;  nb = n0 - 2048; }
  else                { W = W2; Nw = 512;  nb = n0 - 2560; }
  int t = threadIdx.x;
  int col = t & 31, r8 = t >> 5;
#pragma unroll
  for (int p = 0; p < 8; ++p) {
    int kk = p * 8 + r8;
    tile[kk][col] = W[(size_t)(KT * 64 + kk) * Nw + nb + col];
  }
  __syncthreads();
  int e = t >> 6, l = t & 63;
  int nf = e >> 1, ks = e & 1;
  ushort4 o0, o1;
  unsigned short* op = (unsigned short*)&o0;
#pragma unroll
  for (int j = 0; j < 8; ++j) {
    unsigned short v = f2bf(tile[ks * 32 + (l >> 4) * 8 + j][nf * 16 + (l & 15)]);
    if (j < 4) op[j] = v; else ((unsigned short*)&o1)[j - 4] = v;
  }
  unsigned short* dst = out + (((size_t)(c >> 3) * 32 + ngroup * 4 + e) << 9) + l * 8;
  *(ushort4*)dst = o0;
  *(ushort4*)(dst + 4) = o1;
}

// ---------------- V transpose: P1 v-region (b,s | kv,d) -> Vt[b][kv][d][s] ----------------
__global__ __launch_bounds__(256) void vtrans_kernel(const unsigned short* __restrict__ P1,
                                                     unsigned short* __restrict__ Vt) {
  __shared__ unsigned short tile[32][33];
  int s0 = blockIdx.x * 32, d0 = blockIdx.y * 32, bk = blockIdx.z;
  int b = bk >> 3, kv = bk & 7;
  int tx = threadIdx.x & 31, ty = threadIdx.x >> 5;
#pragma unroll
  for (int i = 0; i < 32; i += 8)
    tile[ty + i][tx] = P1[(size_t)(b * S_ + s0 + ty + i) * 3072 + 2560 + kv * 64 + d0 + tx];
  __syncthreads();
#pragma unroll
  for (int i = 0; i < 32; i += 8)
    Vt[(size_t)(bk * 64 + d0 + ty + i) * S_ + s0 + tx] = tile[tx][ty + i];
}

// ---------------- RoPE combine: Q = rope(P1q+P2q)*SCALE, K = rope(P1k+P2k) ----------------
__global__ __launch_bounds__(256) void combine_rope(const unsigned short* __restrict__ P1,
                                                    const unsigned short* __restrict__ P2,
                                                    const float* __restrict__ cosT,
                                                    const float* __restrict__ sinT,
                                                    unsigned short* __restrict__ Qb,
                                                    unsigned short* __restrict__ Kb) {
  int id = blockIdx.x * 256 + threadIdx.x;
  int row = id / 640;
  int grp = id - row * 640;
  int b = row >> 11;
  int s = row & 2047;
  bool isQ = grp < 512;
  int n = isQ ? grp * 4 : (grp - 512) * 4;
  int h = n >> 6;
  int d = n & 63;
  int base = isQ ? 0 : 2048;
  const int ld1 = 3072, ld2 = 2560;
  int pd = (d < 32) ? d + 32 : d - 32;
  float sign = (d < 32) ? -1.f : 1.f;
  int pcol = base + h * 64 + pd;

  ushort4 a1 = *(const ushort4*)&P1[(size_t)row * ld1 + base + n];
  ushort4 a2 = *(const ushort4*)&P2[(size_t)row * ld2 + base + n];
  ushort4 b1 = *(const ushort4*)&P1[(size_t)row * ld1 + pcol];
  ushort4 b2 = *(const ushort4*)&P2[(size_t)row * ld2 + pcol];
  float4 cv = *(const float4*)&cosT[(size_t)row * 64 + d];
  float4 sv = *(const float4*)&sinT[(size_t)row * 64 + d];
  float scale = isQ ? 0.125f : 1.0f;

  float xs[4] = { bf2f(a1.x) + bf2f(a2.x), bf2f(a1.y) + bf2f(a2.y),
                  bf2f(a1.z) + bf2f(a2.z), bf2f(a1.w) + bf2f(a2.w) };
  float xp[4] = { bf2f(b1.x) + bf2f(b2.x), bf2f(b1.y) + bf2f(b2.y),
                  bf2f(b1.z) + bf2f(b2.z), bf2f(b1.w) + bf2f(b2.w) };
  float cc[4] = { cv.x, cv.y, cv.z, cv.w };
  float ss[4] = { sv.x, sv.y, sv.z, sv.w };
  ushort4 o;
  unsigned short* op = (unsigned short*)&o;
#pragma unroll
  for (int i = 0; i < 4; ++i)
    op[i] = f2bf((xs[i] * cc[i] + sign * xp[i] * ss[i]) * scale);

  if (isQ)
    *(ushort4*)&Qb[((size_t)(b * NH_ + h) * S_ + s) * HD_ + d] = o;
  else
    *(ushort4*)&Kb[((size_t)(b * NKV_ + h) * S_ + s) * HD_ + d] = o;
}

// ================= 256x256 GEMM, pipelined 4-phase, contiguous frag-tile staging =================
#define RD_A(BC, MH) do { \
  _Pragma("unroll") for (int mf = 0; mf < 4; ++mf) { \
    _Pragma("unroll") for (int ks = 0; ks < 2; ++ks) \
      a[mf][ks] = *(const short8*)&lds[BC][((wm * 2 + (MH)) * 8 + mf * 2 + ks) * 512 + l * 8]; \
  } \
} while (0)

#define RD_B(BC, NH, DST) do { \
  _Pragma("unroll") for (int nf = 0; nf < 2; ++nf) { \
    _Pragma("unroll") for (int ks = 0; ks < 2; ++ks) \
      DST[nf][ks] = *(const short8*)&lds[BC][16384 + (((wn * 2 + (NH)) * 2 + nf) * 2 + ks) * 512 + l * 8]; \
  } \
} while (0)

#define MM(MH, NH, BB) do { \
  _Pragma("unroll") for (int mf = 0; mf < 4; ++mf) { \
    _Pragma("unroll") for (int nf = 0; nf < 2; ++nf) { \
      _Pragma("unroll") for (int ks = 0; ks < 2; ++ks) \
        acc[(MH) * 4 + mf][(NH) * 2 + nf] = __builtin_amdgcn_mfma_f32_16x16x32_bf16( \
            a[mf][ks], BB[nf][ks], acc[(MH) * 4 + mf][(NH) * 2 + nf], 0, 0, 0); \
    } \
  } \
} while (0)

#define STAGE_A(H, KT) do { \
  int bq_ = (KT) & 1; \
  int d1_ = (H) * 8 + w; \
  gload_lds16(aF + (((size_t)((KT) * 32 + d1_)) << 9), &lds[bq_][d1_ * 512]); \
  gload_lds16(aF + (((size_t)((KT) * 32 + 16 + d1_)) << 9), &lds[bq_][(16 + d1_) * 512]); \
} while (0)

#define STAGE_B(H, KT) do { \
  int bq_ = (KT) & 1; \
  int e1_ = (w >> 2) * 8 + (H) * 4 + (w & 3); \
  gload_lds16(bF + (((size_t)((KT) * 32 + e1_)) << 9), &lds[bq_][16384 + e1_ * 512]); \
  gload_lds16(bF + (((size_t)((KT) * 32 + 16 + e1_)) << 9), &lds[bq_][16384 + (16 + e1_) * 512]); \
} while (0)

#define GROUP_P(BC, G) do { \
  int kt1 = (G) + 1; if (kt1 > 31) kt1 = 31; \
  int kt2 = (G) + 2; if (kt2 > 31) kt2 = 31; \
  int BN_ = kt1 & 1; \
  BARF(); \
  __builtin_amdgcn_s_setprio(1); MM(0, 0, b0); __builtin_amdgcn_s_setprio(0); \
  RD_B(BC, 1, b1); \
  STAGE_A(1, kt1); \
  BARF(); \
  __builtin_amdgcn_s_setprio(1); MM(0, 1, b1); __builtin_amdgcn_s_setprio(0); \
  STAGE_A(0, kt2); \
  BARF(); \
  RD_A(BC, 1); \
  __builtin_amdgcn_s_setprio(1); MM(1, 0, b0); __builtin_amdgcn_s_setprio(0); \
  STAGE_B(0, kt2); \
  asm volatile("s_waitcnt vmcnt(8)" ::: "memory"); \
  BARF(); \
  __builtin_amdgcn_s_setprio(1); MM(1, 1, b1); __builtin_amdgcn_s_setprio(0); \
  RD_A(BN_, 0); \
  RD_B(BN_, 0, b0); \
  STAGE_B(1, kt2); \
  asm volatile("s_waitcnt vmcnt(6)" ::: "memory"); \
} while (0)

__global__ __launch_bounds__(512, 2) void gemm256(const unsigned short* __restrict__ Afr,
                                                  const unsigned short* __restrict__ Wfr,
                                                  void* __restrict__ Cv,
                                                  int N, int nbx) {
  __shared__ unsigned short lds[2][32768];
  int nwg = gridDim.x;
  int orig = blockIdx.x;
  int wgid = (orig & 7) * (nwg >> 3) + (orig >> 3);
  int bn = wgid % nbx, bm = wgid / nbx;
  int t = threadIdx.x, w = t >> 6, l = t & 63;
  int wm = w >> 2, wn = w & 3;

  const unsigned short* aF = Afr + ((size_t)bm << 19) + l * 8;
  const unsigned short* bF = Wfr + ((size_t)bn << 19) + l * 8;

  short8 a[4][2], b0[2][2], b1[2][2];
  f32x4 acc[8][4];
#pragma unroll
  for (int mi = 0; mi < 8; ++mi)
#pragma unroll
    for (int ni = 0; ni < 4; ++ni) acc[mi][ni] = 0.f;

  STAGE_A(0, 0); STAGE_A(1, 0); STAGE_B(0, 0); STAGE_B(1, 0);
  STAGE_A(0, 1); STAGE_B(0, 1); STAGE_B(1, 1);
  asm volatile("s_waitcnt vmcnt(6)" ::: "memory");
  BARF();
  RD_A(0, 0);
  RD_B(0, 0, b0);

  for (int tg = 0; tg < 32; tg += 2) {
    GROUP_P(0, tg);
    GROUP_P(1, tg + 1);
  }
  asm volatile("s_waitcnt vmcnt(0)" ::: "memory");

#pragma unroll
  for (int mi = 0; mi < 8; ++mi) {
    int row = bm * 256 + wm * 128 + (mi >> 2) * 64 + (mi & 3) * 16 + (l >> 4) * 4;
#pragma unroll
    for (int ni = 0; ni < 4; ++ni) {
      int col = bn * 256 + wn * 64 + (ni >> 1) * 32 + (ni & 1) * 16 + (l & 15);
#pragma unroll
      for (int r = 0; r < 4; ++r)
        ((unsigned short*)Cv)[(size_t)(row + r) * N + col] = f2bf(acc[mi][ni][r]);
    }
  }
}

// ================= out-proj GEMM: BM=128 x BN=256, row-major A + frag B, f32 out =================
#define RD_AO(BC) do { \
  _Pragma("unroll") for (int mf = 0; mf < 4; ++mf) { \
    _Pragma("unroll") for (int ks = 0; ks < 2; ++ks) \
      a[mf][ks] = *(const short8*)&lds3[BC][(wm * 8 + mf * 2 + ks) * 512 + l * 8]; \
  } \
} while (0)

#define RD_BO(BC, NH, DST) do { \
  _Pragma("unroll") for (int nf = 0; nf < 2; ++nf) { \
    _Pragma("unroll") for (int ks = 0; ks < 2; ++ks) \
      DST[nf][ks] = *(const short8*)&lds3[BC][8192 + (((wn * 2 + (NH)) * 2 + nf) * 2 + ks) * 512 + l * 8]; \
  } \
} while (0)

#define MM_O(NH, BB) do { \
  _Pragma("unroll") for (int mf = 0; mf < 4; ++mf) { \
    _Pragma("unroll") for (int nf = 0; nf < 2; ++nf) { \
      _Pragma("unroll") for (int ks = 0; ks < 2; ++ks) \
        acc[mf][(NH) * 2 + nf] = __builtin_amdgcn_mfma_f32_16x16x32_bf16( \
            a[mf][ks], BB[nf][ks], acc[mf][(NH) * 2 + nf], 0, 0, 0); \
    } \
  } \
} while (0)

#define STAGE_AO(KT) do { \
  int bq_ = (KT) & 1; \
  gload_lds16(aRM + (size_t)(KT) * 64, &lds3[bq_][w * 512]); \
  gload_lds16(aRM + (size_t)64 * 2048 + (size_t)(KT) * 64, &lds3[bq_][(8 + w) * 512]); \
} while (0)

#define STAGE_BO(H, KT) do { \
  int bq_ = (KT) & 1; \
  int e1_ = (w >> 2) * 8 + (H) * 4 + (w & 3); \
  gload_lds16(bF + (((size_t)((KT) * 32 + e1_)) << 9), &lds3[bq_][8192 + e1_ * 512]); \
  gload_lds16(bF + (((size_t)((KT) * 32 + 16 + e1_)) << 9), &lds3[bq_][8192 + (16 + e1_) * 512]); \
} while (0)

#define GROUPO(BC, G) do { \
  int kt1 = (G) + 1; if (kt1 > 31) kt1 = 31; \
  int kt2 = (G) + 2; if (kt2 > 31) kt2 = 31; \
  RD_AO(BC); RD_BO(BC, 0, b0); \
  STAGE_BO(1, kt1); \
  BARF(); \
  __builtin_amdgcn_s_setprio(1); MM_O(0, b0); __builtin_amdgcn_s_setprio(0); \
  BARF(); \
  RD_BO(BC, 1, b1); \
  STAGE_AO(kt2); STAGE_BO(0, kt2); \
  BARF(); \
  __builtin_amdgcn_s_setprio(1); MM_O(1, b1); __builtin_amdgcn_s_setprio(0); \
  asm volatile("s_waitcnt vmcnt(4)" ::: "memory"); \
  BARF(); \
} while (0)

__global__ __launch_bounds__(512, 2) void gemm_op(const unsigned short* __restrict__ Arm,
                                                  const unsigned short* __restrict__ Wfr,
                                                  float* __restrict__ C,
                                                  int N, int nbx) {
  __shared__ unsigned short lds3[2][24576];
  int nwg = gridDim.x;
  int orig = blockIdx.x;
  int wgid = (orig & 7) * (nwg >> 3) + (orig >> 3);
  int bn = wgid % nbx, bm = wgid / nbx;
  int t = threadIdx.x, w = t >> 6, l = t & 63;
  int wm = w >> 2, wn = w & 3;

  const unsigned short* aRM = Arm +
      (size_t)(bm * 128 + ((w >> 1) & 3) * 16 + (l & 15)) * 2048 + (w & 1) * 32 + (l >> 4) * 8;
  const unsigned short* bF = Wfr + ((size_t)bn << 19) + l * 8;

  short8 a[4][2], b0[2][2], b1[2][2];
  f32x4 acc[4][4];
#pragma unroll
  for (int mi = 0; mi < 4; ++mi)
#pragma unroll
    for (int ni = 0; ni < 4; ++ni) acc[mi][ni] = 0.f;

  STAGE_AO(0); STAGE_BO(0, 0); STAGE_BO(1, 0);
  STAGE_AO(1); STAGE_BO(0, 1);
  asm volatile("s_waitcnt vmcnt(4)" ::: "memory");
  BARF();

  for (int tg = 0; tg < 32; tg += 2) {
    GROUPO(0, tg);
    GROUPO(1, tg + 1);
  }
  asm volatile("s_waitcnt vmcnt(0)" ::: "memory");

#pragma unroll
  for (int mf = 0; mf < 4; ++mf) {
    int row = bm * 128 + wm * 64 + mf * 16 + (l >> 4) * 4;
#pragma unroll
    for (int ni = 0; ni < 4; ++ni) {
      int col = bn * 256 + wn * 64 + (ni >> 1) * 32 + (ni & 1) * 16 + (l & 15);
#pragma unroll
      for (int r = 0; r < 4; ++r)
        C[(size_t)(row + r) * N + col] = acc[mf][ni][r];
    }
  }
}

// ---------------- causal GQA flash attention: 4-warp blocks, natural causal extent ----------------
// 1024 blocks (16 q-segments x 32 heads x 2 batch), LPT-ordered (longest qb first).
// Per-warp compute is verbatim from the R8/R11-validated kernel; only block geometry and
// the 256-thread staging lane-split changed.
__global__ __launch_bounds__(256) void attn_kernel(const unsigned short* __restrict__ Q,
                                                   const unsigned short* __restrict__ K,
                                                   const unsigned short* __restrict__ Vt,
                                                   unsigned short* __restrict__ attnOut) {
  __shared__ unsigned short lK[2][64 * 64];
  __shared__ unsigned short lV[2][64 * 64];

  int bx = blockIdx.x;
  int qb = 15 - (bx >> 6);        // LPT: longest blocks dispatched first
  int hh = bx & 63;
  int head = hh & 31;
  int b = hh >> 5;
  int kvh = head >> 2;
  const unsigned short* Kp = K + (size_t)(b * NKV_ + kvh) * S_ * HD_;
  const unsigned short* Vp = Vt + (size_t)(b * NKV_ + kvh) * HD_ * S_;

  int t = threadIdx.x;
  int w = t >> 6, l = t & 63;     // w in 0..3
  int q32 = l & 31, hf = l >> 5;
  int qbase_w = qb * 128 + w * 32;
  const unsigned short* Qp = Q + ((size_t)(b * NH_ + head) * S_ + qbase_w) * HD_;

  short8 qf[4];
  {
    const unsigned short* qrow = Qp + (size_t)q32 * HD_ + hf * 8;
#pragma unroll
    for (int kc = 0; kc < 4; ++kc)
      qf[kc] = *(const short8*)(qrow + kc * 16);
  }

  // staging: 256 threads x 2 slots x 16B per matrix = 8KB tile
  int srow = t >> 2;              // 0..63
  int ss0 = t & 3;                // slots ss0 and ss0+4
  unsigned lOff0 = srow * 128 + ((ss0 ^ (srow & 7)) << 4);
  unsigned lOff1 = srow * 128 + (((ss0 + 4) ^ (srow & 7)) << 4);
  const char* gK0 = (const char*)(Kp + (size_t)srow * 64 + ss0 * 8);
  const char* gV0 = (const char*)(Vp + (size_t)srow * 2048 + ss0 * 8);

  {
    int4 rk0 = *(const int4*)(gK0);
    int4 rk1 = *(const int4*)(gK0 + 64);
    int4 rv0 = *(const int4*)(gV0);
    int4 rv1 = *(const int4*)(gV0 + 64);
    *(int4*)((char*)lK[0] + lOff0) = rk0;
    *(int4*)((char*)lK[0] + lOff1) = rk1;
    *(int4*)((char*)lV[0] + lOff0) = rv0;
    *(int4*)((char*)lV[0] + lOff1) = rv1;
  }
  __syncthreads();

  f32x16 oA = 0.f, oB = 0.f;
  float mrun = -1e30f, lrun = 0.f;

  int nt = 2 * qb + 2;
  int cur = 0;
  for (int tI = 0; tI < nt; ++tI) {
    int kv0 = tI * 64;
    bool pf = (tI + 1 < nt);
    int4 nk0, nk1, nv0, nv1;
    if (pf) {
      nk0 = *(const int4*)(gK0 + (size_t)(kv0 + 64) * 128);
      nk1 = *(const int4*)(gK0 + (size_t)(kv0 + 64) * 128 + 64);
      nv0 = *(const int4*)(gV0 + (size_t)(kv0 + 64) * 2);
      nv1 = *(const int4*)(gV0 + (size_t)(kv0 + 64) * 2 + 64);
    }

    if (kv0 <= qbase_w + 31) {
      const char* lKc = (const char*)lK[cur];
      const char* lVc = (const char*)lV[cur];
      int swz = q32 & 7;

      f32x16 sA = 0.f, sB = 0.f;
      __builtin_amdgcn_s_setprio(1);
#pragma unroll
      for (int kc = 0; kc < 4; ++kc) {
        int cs = (kc << 1) | hf;
        short8 ak0 = *(const short8*)(lKc + q32 * 128 + ((cs ^ swz) << 4));
        short8 ak1 = *(const short8*)(lKc + (32 + q32) * 128 + ((cs ^ swz) << 4));
        sA = MFMA32(ak0, qf[kc], sA);
        sB = MFMA32(ak1, qf[kc], sB);
      }
      __builtin_amdgcn_s_setprio(0);

      if (kv0 + 63 > qbase_w) {
        int qg = qbase_w + q32;
#pragma unroll
        for (int r = 0; r < 16; ++r) {
          int kvr = kv0 + (r & 3) + ((r >> 2) << 3) + (hf << 2);
          if (kvr > qg) sA[r] = -1e30f;
          if (kvr + 32 > qg) sB[r] = -1e30f;
        }
      }

      float pmax = sA[0];
#pragma unroll
      for (int r = 1; r < 16; ++r) pmax = fmaxf(pmax, sA[r]);
#pragma unroll
      for (int r = 0; r < 16; ++r) pmax = fmaxf(pmax, sB[r]);
      pmax = fmaxf(pmax, __shfl_xor(pmax, 32, 64));

      if (!__all(pmax <= mrun + 8.f)) {
        float mnew = fmaxf(mrun, pmax);
        float sf = __expf(mrun - mnew);
        lrun *= sf;
        mrun = mnew;
#pragma unroll
        for (int r = 0; r < 16; ++r) {
          int src = (r & 3) + ((r >> 2) << 3) + (hf << 2);
          float sfr = __shfl(sf, src, 64);
          oA[r] *= sfr;
          oB[r] *= sfr;
        }
      }

      float rs = 0.f;
#pragma unroll
      for (int r = 0; r < 16; ++r) { sA[r] = __expf(sA[r] - mrun); rs += sA[r]; }
#pragma unroll
      for (int r = 0; r < 16; ++r) { sB[r] = __expf(sB[r] - mrun); rs += sB[r]; }
      rs += __shfl_xor(rs, 32, 64);
      lrun += rs;

      short8 paf[4];
      {
        unsigned c0 = cvtpk(sA[0], sA[1]), c1 = cvtpk(sA[2], sA[3]);
        unsigned c2 = cvtpk(sA[4], sA[5]), c3 = cvtpk(sA[6], sA[7]);
        pl32swap(c0, c2); pl32swap(c1, c3);
        paf[0] = mkfrag(c0, c1, c2, c3);
      }
      {
        unsigned c0 = cvtpk(sA[8], sA[9]),  c1 = cvtpk(sA[10], sA[11]);
        unsigned c2 = cvtpk(sA[12], sA[13]), c3 = cvtpk(sA[14], sA[15]);
        pl32swap(c0, c2); pl32swap(c1, c3);
        paf[1] = mkfrag(c0, c1, c2, c3);
      }
      {
        unsigned c0 = cvtpk(sB[0], sB[1]), c1 = cvtpk(sB[2], sB[3]);
        unsigned c2 = cvtpk(sB[4], sB[5]), c3 = cvtpk(sB[6], sB[7]);
        pl32swap(c0, c2); pl32swap(c1, c3);
        paf[2] = mkfrag(c0, c1, c2, c3);
      }
      {
        unsigned c0 = cvtpk(sB[8], sB[9]),  c1 = cvtpk(sB[10], sB[11]);
        unsigned c2 = cvtpk(sB[12], sB[13]), c3 = cvtpk(sB[14], sB[15]);
        pl32swap(c0, c2); pl32swap(c1, c3);
        paf[3] = mkfrag(c0, c1, c2, c3);
      }

      __builtin_amdgcn_s_setprio(1);
#pragma unroll
      for (int ks = 0; ks < 4; ++ks) {
        int cs = (ks << 1) | hf;
        short8 v0 = *(const short8*)(lVc + q32 * 128 + ((cs ^ swz) << 4));
        short8 v1 = *(const short8*)(lVc + (32 + q32) * 128 + ((cs ^ swz) << 4));
        oA = MFMA32(paf[ks], v0, oA);
        oB = MFMA32(paf[ks], v1, oB);
      }
      __builtin_amdgcn_s_setprio(0);
    }

    if (pf) {
      *(int4*)((char*)lK[cur ^ 1] + lOff0) = nk0;
      *(int4*)((char*)lK[cur ^ 1] + lOff1) = nk1;
      *(int4*)((char*)lV[cur ^ 1] + lOff0) = nv0;
      *(int4*)((char*)lV[cur ^ 1] + lOff1) = nv1;
    }
    __syncthreads();
    cur ^= 1;
  }

  float linv = 1.f / lrun;
#pragma unroll
  for (int r = 0; r < 16; ++r) {
    int src = (r & 3) + ((r >> 2) << 3) + (hf << 2);
    float li = __shfl(linv, src, 64);
    unsigned short* op = attnOut + ((size_t)(b * S_ + qbase_w + src)) * (NH_ * HD_) + head * 64;
    op[q32] = f2bf(oA[r] * li);
    op[32 + q32] = f2bf(oB[r] * li);
  }
}

extern "C" void kernel_launch(void* const* d_in, const int* in_sizes, int n_in,
                              void* d_out, int out_size, void* d_ws, size_t ws_size,
                              hipStream_t stream) {
  const float* hidden = (const float*)d_in[0];
  const float* bbox   = (const float*)d_in[1];
  const float* cosT   = (const float*)d_in[2];
  const float* sinT   = (const float*)d_in[3];
  const float* Wq  = (const float*)d_in[4];
  const float* Wk  = (const float*)d_in[5];
  const float* Wv  = (const float*)d_in[6];
  const float* Wo  = (const float*)d_in[7];
  const float* Wsq = (const float*)d_in[8];
  const float* Wsk = (const float*)d_in[9];

  char* ws = (char*)d_ws;
  size_t off = 0;
  auto alloc = [&](size_t bytes) {
    void* p = ws + off;
    off += (bytes + 255) & ~(size_t)255;
    return p;
  };
  unsigned short* AfrH = (unsigned short*)alloc((size_t)4096 * 2048 * 2);
  unsigned short* AfrB = (unsigned short*)alloc((size_t)4096 * 2048 * 2);
  unsigned short* WhF  = (unsigned short*)alloc((size_t)3072 * 2048 * 2);
  unsigned short* WbF  = (unsigned short*)alloc((size_t)2560 * 2048 * 2);
  unsigned short* WoF  = (unsigned short*)alloc((size_t)2048 * 2048 * 2);
  unsigned short* P1   = (unsigned short*)alloc((size_t)4096 * 3072 * 2);
  unsigned short* P2   = (unsigned short*)alloc((size_t)4096 * 2560 * 2);
  // aliases into dead regions:
  unsigned short* Qb     = AfrB;
  unsigned short* Kb     = AfrH;
  unsigned short* Vt     = AfrH + (size_t)B_ * NKV_ * S_ * HD_;
  unsigned short* attnRM = WhF;

  dim3 blk(256);
  castA_frag<<<dim3(4096), blk, 0, stream>>>(hidden, AfrH);
  castA_frag<<<dim3(4096), blk, 0, stream>>>(bbox,   AfrB);
  castW_frag<<<dim3(3072), blk, 0, stream>>>(Wq,  Wk,  Wv,      WhF);
  castW_frag<<<dim3(2560), blk, 0, stream>>>(Wsq, Wsk, nullptr, WbF);
  castW_frag<<<dim3(2048), blk, 0, stream>>>(Wo,  Wo,  Wo,      WoF);

  gemm256<<<dim3(192), dim3(512), 0, stream>>>(AfrH, WhF, P1, 3072, 12);
  gemm256<<<dim3(160), dim3(512), 0, stream>>>(AfrB, WbF, P2, 2560, 10);

  combine_rope<<<dim3((B_ * S_ * 640) / 256), blk, 0, stream>>>(P1, P2, cosT, sinT, Qb, Kb);
  vtrans_kernel<<<dim3(64, 2, 16), blk, 0, stream>>>(P1, Vt);

  attn_kernel<<<dim3(1024), dim3(256), 0, stream>>>(Qb, Kb, Vt, attnRM);

  gemm_op<<<dim3(256), dim3(512), 0, stream>>>(attnRM, WoF, (float*)d_out, 2048, 8);
}

// Round 14
// 250.010 us; speedup vs baseline: 1.0476x; 1.0476x over previous
//
#include <hip/hip_runtime.h>

#define B_ 2
#define S_ 2048
#define H_ 2048
#define NH_ 32
#define NKV_ 8
#define HD_ 64

typedef short short8 __attribute__((ext_vector_type(8)));
typedef float f32x4 __attribute__((ext_vector_type(4)));
typedef float f32x16 __attribute__((ext_vector_type(16)));
typedef unsigned int uint4v __attribute__((ext_vector_type(4)));

__device__ __forceinline__ float bf2f(unsigned short u) {
  union { unsigned int i; float f; } v; v.i = ((unsigned int)u) << 16; return v.f;
}
__device__ __forceinline__ unsigned short f2bf(float f) {
  union { float f; unsigned int i; } v; v.f = f;
  unsigned int u = v.i;
  u += 0x7fffu + ((u >> 16) & 1u);
  return (unsigned short)(u >> 16);
}
__device__ __forceinline__ unsigned int cvtpk(float lo, float hi) {
  unsigned int r;
  asm("v_cvt_pk_bf16_f32 %0, %1, %2" : "=v"(r) : "v"(lo), "v"(hi));
  return r;
}
__device__ __forceinline__ void pl32swap(unsigned int& a, unsigned int& b) {
  asm("v_permlane32_swap_b32 %0, %1" : "+v"(a), "+v"(b));
}
__device__ __forceinline__ short8 mkfrag(unsigned a, unsigned b, unsigned c, unsigned d) {
  union { uint4v u; short8 s; } x;
  x.u = (uint4v){a, b, c, d};
  return x.s;
}
__device__ __forceinline__ void gload_lds16(const unsigned short* g, unsigned short* l) {
  __builtin_amdgcn_global_load_lds((const __attribute__((address_space(1))) void*)g,
                                   (__attribute__((address_space(3))) void*)l,
                                   16, 0, 0);
}
#define MFMA32(A, B, C) __builtin_amdgcn_mfma_f32_32x32x16_bf16(A, B, C, 0, 0, 0)
#define BARF() asm volatile("s_barrier" ::: "memory")

// ---------------- A producer: f32 row-major -> bf16 fragment-tile order (BM=256) ----------------
__global__ __launch_bounds__(256) void castA_frag(const float* __restrict__ in,
                                                  unsigned short* __restrict__ out) {
  int c = blockIdx.x * 4 + (threadIdx.x >> 6);   // chunk id [0, 16384)
  int l = threadIdx.x & 63;
  int D = c & 31, KT = (c >> 5) & 31, bm = c >> 10;
  int row = bm * 256 + ((D >> 4) & 1) * 128 + ((D >> 3) & 1) * 64 + ((D >> 1) & 3) * 16 + (l & 15);
  int k = KT * 64 + (D & 1) * 32 + (l >> 4) * 8;
  const float* src = in + (size_t)row * 2048 + k;
  float4 v0 = *(const float4*)src;
  float4 v1 = *(const float4*)(src + 4);
  ushort4 o0, o1;
  o0.x = f2bf(v0.x); o0.y = f2bf(v0.y); o0.z = f2bf(v0.z); o0.w = f2bf(v0.w);
  o1.x = f2bf(v1.x); o1.y = f2bf(v1.y); o1.z = f2bf(v1.z); o1.w = f2bf(v1.w);
  unsigned short* dst = out + (size_t)c * 512 + l * 8;
  *(ushort4*)dst = o0;
  *(ushort4*)(dst + 4) = o1;
}

// ---------------- W producer: f32 W[K][N] (concat cols) -> bf16 fragment-tile (BN=256) ----------------
__global__ __launch_bounds__(256) void castW_frag(const float* __restrict__ W0,
                                                  const float* __restrict__ W1,
                                                  const float* __restrict__ W2,
                                                  unsigned short* __restrict__ out) {
  __shared__ float tile[64][33];
  int c = blockIdx.x;
  int ngroup = c & 7, KT = (c >> 3) & 31, bn = c >> 8;
  int n0 = bn * 256 + ngroup * 32;
  const float* W; int Nw, nb;
  if (n0 < 2048)      { W = W0; Nw = 2048; nb = n0; }
  else if (n0 < 2560) { W = W1; Nw = 512;  nb = n0 - 2048; }
  else                { W = W2; Nw = 512;  nb = n0 - 2560; }
  int t = threadIdx.x;
  int col = t & 31, r8 = t >> 5;
#pragma unroll
  for (int p = 0; p < 8; ++p) {
    int kk = p * 8 + r8;
    tile[kk][col] = W[(size_t)(KT * 64 + kk) * Nw + nb + col];
  }
  __syncthreads();
  int e = t >> 6, l = t & 63;
  int nf = e >> 1, ks = e & 1;
  ushort4 o0, o1;
  unsigned short* op = (unsigned short*)&o0;
#pragma unroll
  for (int j = 0; j < 8; ++j) {
    unsigned short v = f2bf(tile[ks * 32 + (l >> 4) * 8 + j][nf * 16 + (l & 15)]);
    if (j < 4) op[j] = v; else ((unsigned short*)&o1)[j - 4] = v;
  }
  unsigned short* dst = out + (((size_t)(c >> 3) * 32 + ngroup * 4 + e) << 9) + l * 8;
  *(ushort4*)dst = o0;
  *(ushort4*)(dst + 4) = o1;
}

// ---------------- V transpose: P1 v-region (b,s | kv,d) -> Vt[b][kv][d][s] ----------------
__global__ __launch_bounds__(256) void vtrans_kernel(const unsigned short* __restrict__ P1,
                                                     unsigned short* __restrict__ Vt) {
  __shared__ unsigned short tile[32][33];
  int s0 = blockIdx.x * 32, d0 = blockIdx.y * 32, bk = blockIdx.z;
  int b = bk >> 3, kv = bk & 7;
  int tx = threadIdx.x & 31, ty = threadIdx.x >> 5;
#pragma unroll
  for (int i = 0; i < 32; i += 8)
    tile[ty + i][tx] = P1[(size_t)(b * S_ + s0 + ty + i) * 3072 + 2560 + kv * 64 + d0 + tx];
  __syncthreads();
#pragma unroll
  for (int i = 0; i < 32; i += 8)
    Vt[(size_t)(bk * 64 + d0 + ty + i) * S_ + s0 + tx] = tile[tx][ty + i];
}

// ---------------- RoPE combine: Q = rope(P1q+P2q)*SCALE, K = rope(P1k+P2k) ----------------
__global__ __launch_bounds__(256) void combine_rope(const unsigned short* __restrict__ P1,
                                                    const unsigned short* __restrict__ P2,
                                                    const float* __restrict__ cosT,
                                                    const float* __restrict__ sinT,
                                                    unsigned short* __restrict__ Qb,
                                                    unsigned short* __restrict__ Kb) {
  int id = blockIdx.x * 256 + threadIdx.x;
  int row = id / 640;
  int grp = id - row * 640;
  int b = row >> 11;
  int s = row & 2047;
  bool isQ = grp < 512;
  int n = isQ ? grp * 4 : (grp - 512) * 4;
  int h = n >> 6;
  int d = n & 63;
  int base = isQ ? 0 : 2048;
  const int ld1 = 3072, ld2 = 2560;
  int pd = (d < 32) ? d + 32 : d - 32;
  float sign = (d < 32) ? -1.f : 1.f;
  int pcol = base + h * 64 + pd;

  ushort4 a1 = *(const ushort4*)&P1[(size_t)row * ld1 + base + n];
  ushort4 a2 = *(const ushort4*)&P2[(size_t)row * ld2 + base + n];
  ushort4 b1 = *(const ushort4*)&P1[(size_t)row * ld1 + pcol];
  ushort4 b2 = *(const ushort4*)&P2[(size_t)row * ld2 + pcol];
  float4 cv = *(const float4*)&cosT[(size_t)row * 64 + d];
  float4 sv = *(const float4*)&sinT[(size_t)row * 64 + d];
  float scale = isQ ? 0.125f : 1.0f;

  float xs[4] = { bf2f(a1.x) + bf2f(a2.x), bf2f(a1.y) + bf2f(a2.y),
                  bf2f(a1.z) + bf2f(a2.z), bf2f(a1.w) + bf2f(a2.w) };
  float xp[4] = { bf2f(b1.x) + bf2f(b2.x), bf2f(b1.y) + bf2f(b2.y),
                  bf2f(b1.z) + bf2f(b2.z), bf2f(b1.w) + bf2f(b2.w) };
  float cc[4] = { cv.x, cv.y, cv.z, cv.w };
  float ss[4] = { sv.x, sv.y, sv.z, sv.w };
  ushort4 o;
  unsigned short* op = (unsigned short*)&o;
#pragma unroll
  for (int i = 0; i < 4; ++i)
    op[i] = f2bf((xs[i] * cc[i] + sign * xp[i] * ss[i]) * scale);

  if (isQ)
    *(ushort4*)&Qb[((size_t)(b * NH_ + h) * S_ + s) * HD_ + d] = o;
  else
    *(ushort4*)&Kb[((size_t)(b * NKV_ + h) * S_ + s) * HD_ + d] = o;
}

// ================= 256x256 GEMM, pipelined 4-phase, contiguous frag-tile staging =================
#define RD_A(BC, MH) do { \
  _Pragma("unroll") for (int mf = 0; mf < 4; ++mf) { \
    _Pragma("unroll") for (int ks = 0; ks < 2; ++ks) \
      a[mf][ks] = *(const short8*)&lds[BC][((wm * 2 + (MH)) * 8 + mf * 2 + ks) * 512 + l * 8]; \
  } \
} while (0)

#define RD_B(BC, NH, DST) do { \
  _Pragma("unroll") for (int nf = 0; nf < 2; ++nf) { \
    _Pragma("unroll") for (int ks = 0; ks < 2; ++ks) \
      DST[nf][ks] = *(const short8*)&lds[BC][16384 + (((wn * 2 + (NH)) * 2 + nf) * 2 + ks) * 512 + l * 8]; \
  } \
} while (0)

#define MM(MH, NH, BB) do { \
  _Pragma("unroll") for (int mf = 0; mf < 4; ++mf) { \
    _Pragma("unroll") for (int nf = 0; nf < 2; ++nf) { \
      _Pragma("unroll") for (int ks = 0; ks < 2; ++ks) \
        acc[(MH) * 4 + mf][(NH) * 2 + nf] = __builtin_amdgcn_mfma_f32_16x16x32_bf16( \
            a[mf][ks], BB[nf][ks], acc[(MH) * 4 + mf][(NH) * 2 + nf], 0, 0, 0); \
    } \
  } \
} while (0)

#define STAGE_A(H, KT) do { \
  int bq_ = (KT) & 1; \
  int d1_ = (H) * 8 + w; \
  gload_lds16(aF + (((size_t)((KT) * 32 + d1_)) << 9), &lds[bq_][d1_ * 512]); \
  gload_lds16(aF + (((size_t)((KT) * 32 + 16 + d1_)) << 9), &lds[bq_][(16 + d1_) * 512]); \
} while (0)

#define STAGE_B(H, KT) do { \
  int bq_ = (KT) & 1; \
  int e1_ = (w >> 2) * 8 + (H) * 4 + (w & 3); \
  gload_lds16(bF + (((size_t)((KT) * 32 + e1_)) << 9), &lds[bq_][16384 + e1_ * 512]); \
  gload_lds16(bF + (((size_t)((KT) * 32 + 16 + e1_)) << 9), &lds[bq_][16384 + (16 + e1_) * 512]); \
} while (0)

#define GROUP_P(BC, G) do { \
  int kt1 = (G) + 1; if (kt1 > 31) kt1 = 31; \
  int kt2 = (G) + 2; if (kt2 > 31) kt2 = 31; \
  int BN_ = kt1 & 1; \
  BARF(); \
  __builtin_amdgcn_s_setprio(1); MM(0, 0, b0); __builtin_amdgcn_s_setprio(0); \
  RD_B(BC, 1, b1); \
  STAGE_A(1, kt1); \
  BARF(); \
  __builtin_amdgcn_s_setprio(1); MM(0, 1, b1); __builtin_amdgcn_s_setprio(0); \
  STAGE_A(0, kt2); \
  BARF(); \
  RD_A(BC, 1); \
  __builtin_amdgcn_s_setprio(1); MM(1, 0, b0); __builtin_amdgcn_s_setprio(0); \
  STAGE_B(0, kt2); \
  asm volatile("s_waitcnt vmcnt(8)" ::: "memory"); \
  BARF(); \
  __builtin_amdgcn_s_setprio(1); MM(1, 1, b1); __builtin_amdgcn_s_setprio(0); \
  RD_A(BN_, 0); \
  RD_B(BN_, 0, b0); \
  STAGE_B(1, kt2); \
  asm volatile("s_waitcnt vmcnt(6)" ::: "memory"); \
} while (0)

__global__ __launch_bounds__(512, 2) void gemm256(const unsigned short* __restrict__ Afr,
                                                  const unsigned short* __restrict__ Wfr,
                                                  void* __restrict__ Cv,
                                                  int N, int nbx) {
  __shared__ unsigned short lds[2][32768];
  int nwg = gridDim.x;
  int orig = blockIdx.x;
  int wgid = (orig & 7) * (nwg >> 3) + (orig >> 3);
  int bn = wgid % nbx, bm = wgid / nbx;
  int t = threadIdx.x, w = t >> 6, l = t & 63;
  int wm = w >> 2, wn = w & 3;

  const unsigned short* aF = Afr + ((size_t)bm << 19) + l * 8;
  const unsigned short* bF = Wfr + ((size_t)bn << 19) + l * 8;

  short8 a[4][2], b0[2][2], b1[2][2];
  f32x4 acc[8][4];
#pragma unroll
  for (int mi = 0; mi < 8; ++mi)
#pragma unroll
    for (int ni = 0; ni < 4; ++ni) acc[mi][ni] = 0.f;

  STAGE_A(0, 0); STAGE_A(1, 0); STAGE_B(0, 0); STAGE_B(1, 0);
  STAGE_A(0, 1); STAGE_B(0, 1); STAGE_B(1, 1);
  asm volatile("s_waitcnt vmcnt(6)" ::: "memory");
  BARF();
  RD_A(0, 0);
  RD_B(0, 0, b0);

  for (int tg = 0; tg < 32; tg += 2) {
    GROUP_P(0, tg);
    GROUP_P(1, tg + 1);
  }
  asm volatile("s_waitcnt vmcnt(0)" ::: "memory");

#pragma unroll
  for (int mi = 0; mi < 8; ++mi) {
    int row = bm * 256 + wm * 128 + (mi >> 2) * 64 + (mi & 3) * 16 + (l >> 4) * 4;
#pragma unroll
    for (int ni = 0; ni < 4; ++ni) {
      int col = bn * 256 + wn * 64 + (ni >> 1) * 32 + (ni & 1) * 16 + (l & 15);
#pragma unroll
      for (int r = 0; r < 4; ++r)
        ((unsigned short*)Cv)[(size_t)(row + r) * N + col] = f2bf(acc[mi][ni][r]);
    }
  }
}

// ================= out-proj GEMM: BM=128 x BN=256, row-major A + frag B, f32 out =================
#define RD_AO(BC) do { \
  _Pragma("unroll") for (int mf = 0; mf < 4; ++mf) { \
    _Pragma("unroll") for (int ks = 0; ks < 2; ++ks) \
      a[mf][ks] = *(const short8*)&lds3[BC][(wm * 8 + mf * 2 + ks) * 512 + l * 8]; \
  } \
} while (0)

#define RD_BO(BC, NH, DST) do { \
  _Pragma("unroll") for (int nf = 0; nf < 2; ++nf) { \
    _Pragma("unroll") for (int ks = 0; ks < 2; ++ks) \
      DST[nf][ks] = *(const short8*)&lds3[BC][8192 + (((wn * 2 + (NH)) * 2 + nf) * 2 + ks) * 512 + l * 8]; \
  } \
} while (0)

#define MM_O(NH, BB) do { \
  _Pragma("unroll") for (int mf = 0; mf < 4; ++mf) { \
    _Pragma("unroll") for (int nf = 0; nf < 2; ++nf) { \
      _Pragma("unroll") for (int ks = 0; ks < 2; ++ks) \
        acc[mf][(NH) * 2 + nf] = __builtin_amdgcn_mfma_f32_16x16x32_bf16( \
            a[mf][ks], BB[nf][ks], acc[mf][(NH) * 2 + nf], 0, 0, 0); \
    } \
  } \
} while (0)

#define STAGE_AO(KT) do { \
  int bq_ = (KT) & 1; \
  gload_lds16(aRM + (size_t)(KT) * 64, &lds3[bq_][w * 512]); \
  gload_lds16(aRM + (size_t)64 * 2048 + (size_t)(KT) * 64, &lds3[bq_][(8 + w) * 512]); \
} while (0)

#define STAGE_BO(H, KT) do { \
  int bq_ = (KT) & 1; \
  int e1_ = (w >> 2) * 8 + (H) * 4 + (w & 3); \
  gload_lds16(bF + (((size_t)((KT) * 32 + e1_)) << 9), &lds3[bq_][8192 + e1_ * 512]); \
  gload_lds16(bF + (((size_t)((KT) * 32 + 16 + e1_)) << 9), &lds3[bq_][8192 + (16 + e1_) * 512]); \
} while (0)

#define GROUPO(BC, G) do { \
  int kt1 = (G) + 1; if (kt1 > 31) kt1 = 31; \
  int kt2 = (G) + 2; if (kt2 > 31) kt2 = 31; \
  RD_AO(BC); RD_BO(BC, 0, b0); \
  STAGE_BO(1, kt1); \
  BARF(); \
  __builtin_amdgcn_s_setprio(1); MM_O(0, b0); __builtin_amdgcn_s_setprio(0); \
  BARF(); \
  RD_BO(BC, 1, b1); \
  STAGE_AO(kt2); STAGE_BO(0, kt2); \
  BARF(); \
  __builtin_amdgcn_s_setprio(1); MM_O(1, b1); __builtin_amdgcn_s_setprio(0); \
  asm volatile("s_waitcnt vmcnt(4)" ::: "memory"); \
  BARF(); \
} while (0)

__global__ __launch_bounds__(512, 2) void gemm_op(const unsigned short* __restrict__ Arm,
                                                  const unsigned short* __restrict__ Wfr,
                                                  float* __restrict__ C,
                                                  int N, int nbx) {
  __shared__ unsigned short lds3[2][24576];
  int nwg = gridDim.x;
  int orig = blockIdx.x;
  int wgid = (orig & 7) * (nwg >> 3) + (orig >> 3);
  int bn = wgid % nbx, bm = wgid / nbx;
  int t = threadIdx.x, w = t >> 6, l = t & 63;
  int wm = w >> 2, wn = w & 3;

  const unsigned short* aRM = Arm +
      (size_t)(bm * 128 + ((w >> 1) & 3) * 16 + (l & 15)) * 2048 + (w & 1) * 32 + (l >> 4) * 8;
  const unsigned short* bF = Wfr + ((size_t)bn << 19) + l * 8;

  short8 a[4][2], b0[2][2], b1[2][2];
  f32x4 acc[4][4];
#pragma unroll
  for (int mi = 0; mi < 4; ++mi)
#pragma unroll
    for (int ni = 0; ni < 4; ++ni) acc[mi][ni] = 0.f;

  STAGE_AO(0); STAGE_BO(0, 0); STAGE_BO(1, 0);
  STAGE_AO(1); STAGE_BO(0, 1);
  asm volatile("s_waitcnt vmcnt(4)" ::: "memory");
  BARF();

  for (int tg = 0; tg < 32; tg += 2) {
    GROUPO(0, tg);
    GROUPO(1, tg + 1);
  }
  asm volatile("s_waitcnt vmcnt(0)" ::: "memory");

#pragma unroll
  for (int mf = 0; mf < 4; ++mf) {
    int row = bm * 128 + wm * 64 + mf * 16 + (l >> 4) * 4;
#pragma unroll
    for (int ni = 0; ni < 4; ++ni) {
      int col = bn * 256 + wn * 64 + (ni >> 1) * 32 + (ni & 1) * 16 + (l & 15);
#pragma unroll
      for (int r = 0; r < 4; ++r)
        C[(size_t)(row + r) * N + col] = acc[mf][ni][r];
    }
  }
}

// ---------------- causal GQA flash attention (R12-proven: 8-warp paired-segment) ----------------
__global__ __launch_bounds__(512) void attn_kernel(const unsigned short* __restrict__ Q,
                                                   const unsigned short* __restrict__ K,
                                                   const unsigned short* __restrict__ Vt,
                                                   unsigned short* __restrict__ attnOut) {
  __shared__ unsigned short lK[2][64 * 64];
  __shared__ unsigned short lV[2][64 * 64];

  int bx = blockIdx.x;
  int j = bx & 7;
  int bh = bx >> 3;
  int head = bh & 31;
  int b = bh >> 5;
  int kvh = head >> 2;
  const unsigned short* Kp = K + (size_t)(b * NKV_ + kvh) * S_ * HD_;
  const unsigned short* Vp = Vt + (size_t)(b * NKV_ + kvh) * HD_ * S_;

  int t = threadIdx.x;
  int w = t >> 6, l = t & 63;
  int q32 = l & 31, hf = l >> 5;
  int qb_eff = (w < 4) ? j : (15 - j);
  int qbase_w = qb_eff * 128 + (w & 3) * 32;
  const unsigned short* Qp = Q + ((size_t)(b * NH_ + head) * S_ + qbase_w) * HD_;

  short8 qf[4];
  {
    const unsigned short* qrow = Qp + (size_t)q32 * HD_ + hf * 8;
#pragma unroll
    for (int kc = 0; kc < 4; ++kc)
      qf[kc] = *(const short8*)(qrow + kc * 16);
  }

  int srow = t >> 3;
  int sslot = t & 7;
  unsigned lOff = srow * 128 + ((sslot ^ (srow & 7)) << 4);
  const char* gK0 = (const char*)(Kp + (size_t)srow * 64 + sslot * 8);
  const char* gV0 = (const char*)(Vp + (size_t)srow * 2048 + sslot * 8);

  {
    int4 rk = *(const int4*)(gK0);
    int4 rv = *(const int4*)(gV0);
    *(int4*)((char*)lK[0] + lOff) = rk;
    *(int4*)((char*)lV[0] + lOff) = rv;
  }
  __syncthreads();

  f32x16 oA = 0.f, oB = 0.f;
  float mrun = -1e30f, lrun = 0.f;

  int nt = 32 - 2 * j;
  int cur = 0;
  for (int tI = 0; tI < nt; ++tI) {
    int kv0 = tI * 64;
    bool pf = (tI + 1 < nt);
    int4 nk, nv;
    if (pf) {
      nk = *(const int4*)(gK0 + (size_t)(kv0 + 64) * 128);
      nv = *(const int4*)(gV0 + (size_t)(kv0 + 64) * 2);
    }

    if (kv0 <= qbase_w + 31) {
      const char* lKc = (const char*)lK[cur];
      const char* lVc = (const char*)lV[cur];
      int swz = q32 & 7;

      f32x16 sA = 0.f, sB = 0.f;
      __builtin_amdgcn_s_setprio(1);
#pragma unroll
      for (int kc = 0; kc < 4; ++kc) {
        int cs = (kc << 1) | hf;
        short8 ak0 = *(const short8*)(lKc + q32 * 128 + ((cs ^ swz) << 4));
        short8 ak1 = *(const short8*)(lKc + (32 + q32) * 128 + ((cs ^ swz) << 4));
        sA = MFMA32(ak0, qf[kc], sA);
        sB = MFMA32(ak1, qf[kc], sB);
      }
      __builtin_amdgcn_s_setprio(0);

      if (kv0 + 63 > qbase_w) {
        int qg = qbase_w + q32;
#pragma unroll
        for (int r = 0; r < 16; ++r) {
          int kvr = kv0 + (r & 3) + ((r >> 2) << 3) + (hf << 2);
          if (kvr > qg) sA[r] = -1e30f;
          if (kvr + 32 > qg) sB[r] = -1e30f;
        }
      }

      float pmax = sA[0];
#pragma unroll
      for (int r = 1; r < 16; ++r) pmax = fmaxf(pmax, sA[r]);
#pragma unroll
      for (int r = 0; r < 16; ++r) pmax = fmaxf(pmax, sB[r]);
      pmax = fmaxf(pmax, __shfl_xor(pmax, 32, 64));

      if (!__all(pmax <= mrun + 8.f)) {
        float mnew = fmaxf(mrun, pmax);
        float sf = __expf(mrun - mnew);
        lrun *= sf;
        mrun = mnew;
#pragma unroll
        for (int r = 0; r < 16; ++r) {
          int src = (r & 3) + ((r >> 2) << 3) + (hf << 2);
          float sfr = __shfl(sf, src, 64);
          oA[r] *= sfr;
          oB[r] *= sfr;
        }
      }

      float rs = 0.f;
#pragma unroll
      for (int r = 0; r < 16; ++r) { sA[r] = __expf(sA[r] - mrun); rs += sA[r]; }
#pragma unroll
      for (int r = 0; r < 16; ++r) { sB[r] = __expf(sB[r] - mrun); rs += sB[r]; }
      rs += __shfl_xor(rs, 32, 64);
      lrun += rs;

      short8 paf[4];
      {
        unsigned c0 = cvtpk(sA[0], sA[1]), c1 = cvtpk(sA[2], sA[3]);
        unsigned c2 = cvtpk(sA[4], sA[5]), c3 = cvtpk(sA[6], sA[7]);
        pl32swap(c0, c2); pl32swap(c1, c3);
        paf[0] = mkfrag(c0, c1, c2, c3);
      }
      {
        unsigned c0 = cvtpk(sA[8], sA[9]),  c1 = cvtpk(sA[10], sA[11]);
        unsigned c2 = cvtpk(sA[12], sA[13]), c3 = cvtpk(sA[14], sA[15]);
        pl32swap(c0, c2); pl32swap(c1, c3);
        paf[1] = mkfrag(c0, c1, c2, c3);
      }
      {
        unsigned c0 = cvtpk(sB[0], sB[1]), c1 = cvtpk(sB[2], sB[3]);
        unsigned c2 = cvtpk(sB[4], sB[5]), c3 = cvtpk(sB[6], sB[7]);
        pl32swap(c0, c2); pl32swap(c1, c3);
        paf[2] = mkfrag(c0, c1, c2, c3);
      }
      {
        unsigned c0 = cvtpk(sB[8], sB[9]),  c1 = cvtpk(sB[10], sB[11]);
        unsigned c2 = cvtpk(sB[12], sB[13]), c3 = cvtpk(sB[14], sB[15]);
        pl32swap(c0, c2); pl32swap(c1, c3);
        paf[3] = mkfrag(c0, c1, c2, c3);
      }

      __builtin_amdgcn_s_setprio(1);
#pragma unroll
      for (int ks = 0; ks < 4; ++ks) {
        int cs = (ks << 1) | hf;
        short8 v0 = *(const short8*)(lVc + q32 * 128 + ((cs ^ swz) << 4));
        short8 v1 = *(const short8*)(lVc + (32 + q32) * 128 + ((cs ^ swz) << 4));
        oA = MFMA32(paf[ks], v0, oA);
        oB = MFMA32(paf[ks], v1, oB);
      }
      __builtin_amdgcn_s_setprio(0);
    }

    if (pf) {
      *(int4*)((char*)lK[cur ^ 1] + lOff) = nk;
      *(int4*)((char*)lV[cur ^ 1] + lOff) = nv;
    }
    __syncthreads();
    cur ^= 1;
  }

  float linv = 1.f / lrun;
#pragma unroll
  for (int r = 0; r < 16; ++r) {
    int src = (r & 3) + ((r >> 2) << 3) + (hf << 2);
    float li = __shfl(linv, src, 64);
    unsigned short* op = attnOut + ((size_t)(b * S_ + qbase_w + src)) * (NH_ * HD_) + head * 64;
    op[q32] = f2bf(oA[r] * li);
    op[32 + q32] = f2bf(oB[r] * li);
  }
}

extern "C" void kernel_launch(void* const* d_in, const int* in_sizes, int n_in,
                              void* d_out, int out_size, void* d_ws, size_t ws_size,
                              hipStream_t stream) {
  const float* hidden = (const float*)d_in[0];
  const float* bbox   = (const float*)d_in[1];
  const float* cosT   = (const float*)d_in[2];
  const float* sinT   = (const float*)d_in[3];
  const float* Wq  = (const float*)d_in[4];
  const float* Wk  = (const float*)d_in[5];
  const float* Wv  = (const float*)d_in[6];
  const float* Wo  = (const float*)d_in[7];
  const float* Wsq = (const float*)d_in[8];
  const float* Wsk = (const float*)d_in[9];

  char* ws = (char*)d_ws;
  size_t off = 0;
  auto alloc = [&](size_t bytes) {
    void* p = ws + off;
    off += (bytes + 255) & ~(size_t)255;
    return p;
  };
  unsigned short* AfrH = (unsigned short*)alloc((size_t)4096 * 2048 * 2);
  unsigned short* AfrB = (unsigned short*)alloc((size_t)4096 * 2048 * 2);
  unsigned short* WhF  = (unsigned short*)alloc((size_t)3072 * 2048 * 2);
  unsigned short* WbF  = (unsigned short*)alloc((size_t)2560 * 2048 * 2);
  unsigned short* WoF  = (unsigned short*)alloc((size_t)2048 * 2048 * 2);
  unsigned short* P1   = (unsigned short*)alloc((size_t)4096 * 3072 * 2);
  unsigned short* P2   = (unsigned short*)alloc((size_t)4096 * 2560 * 2);
  // aliases into dead regions:
  unsigned short* Qb     = AfrB;
  unsigned short* Kb     = AfrH;
  unsigned short* Vt     = AfrH + (size_t)B_ * NKV_ * S_ * HD_;
  unsigned short* attnRM = WhF;

  dim3 blk(256);
  castA_frag<<<dim3(4096), blk, 0, stream>>>(hidden, AfrH);
  castA_frag<<<dim3(4096), blk, 0, stream>>>(bbox,   AfrB);
  castW_frag<<<dim3(3072), blk, 0, stream>>>(Wq,  Wk,  Wv,      WhF);
  castW_frag<<<dim3(2560), blk, 0, stream>>>(Wsq, Wsk, nullptr, WbF);
  castW_frag<<<dim3(2048), blk, 0, stream>>>(Wo,  Wo,  Wo,      WoF);

  gemm256<<<dim3(192), dim3(512), 0, stream>>>(AfrH, WhF, P1, 3072, 12);
  gemm256<<<dim3(160), dim3(512), 0, stream>>>(AfrB, WbF, P2, 2560, 10);

  combine_rope<<<dim3((B_ * S_ * 640) / 256), blk, 0, stream>>>(P1, P2, cosT, sinT, Qb, Kb);
  vtrans_kernel<<<dim3(64, 2, 16), blk, 0, stream>>>(P1, Vt);

  attn_kernel<<<dim3(512), dim3(512), 0, stream>>>(Qb, Kb, Vt, attnRM);

  gemm_op<<<dim3(256), dim3(512), 0, stream>>>(attnRM, WoF, (float*)d_out, 2048, 8);
}